// Round 1
// baseline (1972.142 us; speedup 1.0000x reference)
//
#include <hip/hip_runtime.h>
#include <math.h>

#define B_  16
#define H_  512
#define L_  2048
#define N2_ 32
#define NC_ 16
#define LC_ 128   // L_/NC_
#define PI_ 3.14159265358979323846f

// ---------------------------------------------------------------------------
// K0: per-(h,n) table: lambda = exp(dt*A), C' = (C_re+iC_im)*(lambda-1)/A
// tab[h*N2+n] = {lr, li, Cr', Ci'}
// ---------------------------------------------------------------------------
__global__ void k0_table(const float* __restrict__ log_dt,
                         const float* __restrict__ C_re,
                         const float* __restrict__ C_im,
                         float4* __restrict__ tab) {
    int idx = blockIdx.x * blockDim.x + threadIdx.x;   // h*N2 + n
    if (idx >= H_ * N2_) return;
    int h = idx >> 5, n = idx & 31;
    float dt = expf(log_dt[h]);
    float e  = expf(-0.5f * dt);
    float th = PI_ * (float)n * dt;
    float lr = e * cosf(th), li = e * sinf(th);
    float ar = -0.5f, ai = PI_ * (float)n;
    float den = ar * ar + ai * ai;
    float x = lr - 1.0f, y = li;
    // (lambda-1)/A = (x+iy)*conj(A)/|A|^2
    float nr = (x * ar + y * ai) / den;
    float ni = (y * ar - x * ai) / den;
    float cr = C_re[idx], ci = C_im[idx];
    tab[idx] = make_float4(lr, li, cr * nr - ci * ni, cr * ni + ci * nr);
}

// ---------------------------------------------------------------------------
// K1: chunk-local recurrence from zero state. One thread per (b,h,c).
// Writes y_local into g, end-state into ES.
// ---------------------------------------------------------------------------
__global__ void __launch_bounds__(256)
k1_chunk(const float* __restrict__ u, const float4* __restrict__ tab,
         float* __restrict__ g, float2* __restrict__ ES) {
    int t = blockIdx.x * 256 + threadIdx.x;   // b*(H*NC) + h*NC + c
    int c = t & (NC_ - 1);
    int h = (t >> 4) & (H_ - 1);
    int b = t >> 13;

    float lr[N2_], li[N2_], Cr[N2_], Ci[N2_], sr[N2_], si[N2_];
#pragma unroll
    for (int n = 0; n < N2_; ++n) {
        float4 v = tab[h * N2_ + n];
        lr[n] = v.x; li[n] = v.y; Cr[n] = v.z; Ci[n] = v.w;
        sr[n] = 0.0f; si[n] = 0.0f;
    }
    size_t base = ((size_t)(b * H_ + h)) * L_ + (size_t)c * LC_;
    const float* up = u + base;
    float* gp = g + base;

    for (int l = 0; l < LC_; l += 4) {
        float4 u4 = *(const float4*)(up + l);
        float uv[4] = {u4.x, u4.y, u4.z, u4.w};
        float yv[4];
#pragma unroll
        for (int j = 0; j < 4; ++j) {
            float a0 = 0.f, a1 = 0.f, a2 = 0.f, a3 = 0.f;
            float uj = uv[j];
#pragma unroll
            for (int n = 0; n < N2_; ++n) {
                float nsr = fmaf(lr[n], sr[n], fmaf(-li[n], si[n], uj));
                float nsi = fmaf(lr[n], si[n], li[n] * sr[n]);
                sr[n] = nsr; si[n] = nsi;
                float term = fmaf(Cr[n], nsr, -Ci[n] * nsi);
                if ((n & 3) == 0) a0 += term;
                else if ((n & 3) == 1) a1 += term;
                else if ((n & 3) == 2) a2 += term;
                else a3 += term;
            }
            yv[j] = 2.0f * ((a0 + a1) + (a2 + a3));
        }
        *(float4*)(gp + l) = make_float4(yv[0], yv[1], yv[2], yv[3]);
    }
    float2* es = ES + (size_t)t * N2_;
#pragma unroll
    for (int n = 0; n < N2_; ++n) es[n] = make_float2(sr[n], si[n]);
}

// ---------------------------------------------------------------------------
// K2: per-(b,h,n) serial scan over chunks: S(c) = lam^Lc * S(c-1) + E(c-1).
// In-place: ES slot c is read (=E(c)) then overwritten with S(c).
// ---------------------------------------------------------------------------
__global__ void k2_scan(const float* __restrict__ log_dt, float2* __restrict__ ES) {
    int t = blockIdx.x * 256 + threadIdx.x;   // bh*N2 + n
    if (t >= B_ * H_ * N2_) return;
    int n  = t & 31;
    int h  = (t >> 5) & (H_ - 1);
    int bh = t >> 5;
    float dt = expf(log_dt[h]);
    float e  = expf(-0.5f * dt * (float)LC_);
    float th = PI_ * (float)n * dt * (float)LC_;
    float Lr = e * cosf(th), Li = e * sinf(th);
    float cr = 0.0f, ci = 0.0f;
    float2* base = ES + (size_t)bh * NC_ * N2_ + n;
#pragma unroll
    for (int c = 0; c < NC_; ++c) {
        float2 Ev = base[(size_t)c * N2_];
        base[(size_t)c * N2_] = make_float2(cr, ci);
        float ncr = fmaf(Lr, cr, fmaf(-Li, ci, Ev.x));
        float nci = fmaf(Lr, ci, fmaf(Li, cr, Ev.y));
        cr = ncr; ci = nci;
    }
}

// ---------------------------------------------------------------------------
// K3: add carry correction 2Re sum_n C'_n lam^(l+1) S_n, add u*D, exact GELU.
// One thread per (b,h,c), same mapping as K1. g updated in place.
// ---------------------------------------------------------------------------
__global__ void __launch_bounds__(256)
k3_fix(const float* __restrict__ u, const float* __restrict__ D,
       const float4* __restrict__ tab, const float2* __restrict__ ES,
       float* __restrict__ g) {
    int t = blockIdx.x * 256 + threadIdx.x;
    int c = t & (NC_ - 1);
    int h = (t >> 4) & (H_ - 1);
    int b = t >> 13;

    float lr[N2_], li[N2_], Cr[N2_], Ci[N2_], pr[N2_], pi[N2_];
    const float2* es = ES + (size_t)t * N2_;
#pragma unroll
    for (int n = 0; n < N2_; ++n) {
        float4 v = tab[h * N2_ + n];
        lr[n] = v.x; li[n] = v.y; Cr[n] = v.z; Ci[n] = v.w;
        float2 S = es[n];
        // p = lambda * S   (lam^(l+1) S at l=0)
        pr[n] = fmaf(lr[n], S.x, -li[n] * S.y);
        pi[n] = fmaf(lr[n], S.y,  li[n] * S.x);
    }
    float d = D[h];
    size_t base = ((size_t)(b * H_ + h)) * L_ + (size_t)c * LC_;
    const float* up = u + base;
    float* gp = g + base;

    for (int l = 0; l < LC_; l += 4) {
        float4 u4 = *(const float4*)(up + l);
        float4 g4 = *(const float4*)(gp + l);
        float uv[4] = {u4.x, u4.y, u4.z, u4.w};
        float gv[4] = {g4.x, g4.y, g4.z, g4.w};
        float ov[4];
#pragma unroll
        for (int j = 0; j < 4; ++j) {
            float a0 = 0.f, a1 = 0.f, a2 = 0.f, a3 = 0.f;
#pragma unroll
            for (int n = 0; n < N2_; ++n) {
                float term = fmaf(Cr[n], pr[n], -Ci[n] * pi[n]);
                if ((n & 3) == 0) a0 += term;
                else if ((n & 3) == 1) a1 += term;
                else if ((n & 3) == 2) a2 += term;
                else a3 += term;
                float npr = fmaf(lr[n], pr[n], -li[n] * pi[n]);
                float npi = fmaf(lr[n], pi[n],  li[n] * pr[n]);
                pr[n] = npr; pi[n] = npi;
            }
            float corr = 2.0f * ((a0 + a1) + (a2 + a3));
            float yv = gv[j] + corr + d * uv[j];
            // exact GELU: 0.5*y*(1+erf(y/sqrt(2)))
            ov[j] = 0.5f * yv * (1.0f + erff(yv * 0.70710678118654752f));
        }
        *(float4*)(gp + l) = make_float4(ov[0], ov[1], ov[2], ov[3]);
    }
}

// ---------------------------------------------------------------------------
// Simple f32 tiled GEMM: C[M,N] = act(A[M,K] @ B[K,N] + bias)
// 64x64 tile, BK=16, 256 threads, 4x4 per thread. M,N,K multiples of 64/16.
// ---------------------------------------------------------------------------
template<bool TANH>
__global__ void __launch_bounds__(256)
gemm_bias_act(const float* __restrict__ A, const float* __restrict__ Bm,
              const float* __restrict__ bias, float* __restrict__ C,
              int M, int N, int K) {
    const int BM = 64, BN = 64, BK = 16;
    __shared__ float As[BK][BM];
    __shared__ float Bs[BK][BN];
    int tid = threadIdx.x;
    int tx = tid & 15, ty = tid >> 4;
    int row0 = blockIdx.y * BM, col0 = blockIdx.x * BN;

    int arow = tid >> 2;          // 0..63
    int acol = (tid & 3) * 4;     // 0,4,8,12
    int brow = tid >> 4;          // 0..15
    int bcol = (tid & 15) * 4;    // 0..60

    float acc[4][4] = {};
    for (int k0 = 0; k0 < K; k0 += BK) {
        float4 av = *(const float4*)&A[(size_t)(row0 + arow) * K + k0 + acol];
        float4 bv = *(const float4*)&Bm[(size_t)(k0 + brow) * N + col0 + bcol];
        As[acol + 0][arow] = av.x;
        As[acol + 1][arow] = av.y;
        As[acol + 2][arow] = av.z;
        As[acol + 3][arow] = av.w;
        *(float4*)&Bs[brow][bcol] = bv;
        __syncthreads();
#pragma unroll
        for (int kk = 0; kk < BK; ++kk) {
            float4 a = *(const float4*)&As[kk][ty * 4];
            float4 b = *(const float4*)&Bs[kk][tx * 4];
            float avv[4] = {a.x, a.y, a.z, a.w};
            float bvv[4] = {b.x, b.y, b.z, b.w};
#pragma unroll
            for (int i = 0; i < 4; ++i)
#pragma unroll
                for (int j = 0; j < 4; ++j)
                    acc[i][j] = fmaf(avv[i], bvv[j], acc[i][j]);
        }
        __syncthreads();
    }
#pragma unroll
    for (int i = 0; i < 4; ++i) {
        int r = row0 + ty * 4 + i;
        float* op = &C[(size_t)r * N + col0 + tx * 4];
        float4 bb = *(const float4*)&bias[col0 + tx * 4];
        float bv[4] = {bb.x, bb.y, bb.z, bb.w};
        float vals[4];
#pragma unroll
        for (int j = 0; j < 4; ++j) {
            float v = acc[i][j] + bv[j];
            vals[j] = TANH ? tanhf(v) : v;
        }
        *(float4*)op = make_float4(vals[0], vals[1], vals[2], vals[3]);
    }
}

// ---------------------------------------------------------------------------
extern "C" void kernel_launch(void* const* d_in, const int* in_sizes, int n_in,
                              void* d_out, int out_size, void* d_ws, size_t ws_size,
                              hipStream_t stream) {
    const float* u     = (const float*)d_in[0];
    const float* D     = (const float*)d_in[1];
    const float* logdt = (const float*)d_in[2];
    const float* C_re  = (const float*)d_in[3];
    const float* C_im  = (const float*)d_in[4];
    const float* W1    = (const float*)d_in[5];
    const float* b1    = (const float*)d_in[6];
    const float* W2    = (const float*)d_in[7];
    const float* b2    = (const float*)d_in[8];
    float* out = (float*)d_out;

    float*  ws  = (float*)d_ws;
    float4* tab = (float4*)ws;                                  // H*N2 float4
    float*  g   = ws + (size_t)H_ * N2_ * 4;                    // B*H*L
    float*  tbuf= g  + (size_t)B_ * H_ * L_;                    // B*H*2H
    float2* ES  = (float2*)(tbuf + (size_t)B_ * H_ * 2 * H_);   // B*H*NC*N2 cplx

    k0_table<<<(H_ * N2_ + 255) / 256, 256, 0, stream>>>(logdt, C_re, C_im, tab);
    k1_chunk<<<B_ * H_ * NC_ / 256, 256, 0, stream>>>(u, tab, g, ES);
    k2_scan<<<B_ * H_ * N2_ / 256, 256, 0, stream>>>(logdt, ES);
    k3_fix<<<B_ * H_ * NC_ / 256, 256, 0, stream>>>(u, D, tab, ES, g);

    gemm_bias_act<true ><<<dim3(2 * H_ / 64, B_ * H_ / 64), 256, 0, stream>>>(
        g, W1, b1, tbuf, B_ * H_, 2 * H_, L_);
    gemm_bias_act<false><<<dim3(H_ / 64, B_ * H_ / 64), 256, 0, stream>>>(
        tbuf, W2, b2, out, B_ * H_, H_, 2 * H_);
}

// Round 2
// 827.038 us; speedup vs baseline: 2.3846x; 2.3846x over previous
//
#include <hip/hip_runtime.h>
#include <math.h>

#define B_  16
#define H_  512
#define L_  2048
#define N2_ 32
#define NC_ 16
#define LC_ 128   // L_/NC_
#define PI_ 3.14159265358979323846f

// ---------------------------------------------------------------------------
// K0: per-(h,n) table: lambda = exp(dt*A), C' = (C_re+iC_im)*(lambda-1)/A
// tab[h*N2+n] = {lr, li, Cr', Ci'}
// ---------------------------------------------------------------------------
__global__ void k0_table(const float* __restrict__ log_dt,
                         const float* __restrict__ C_re,
                         const float* __restrict__ C_im,
                         float4* __restrict__ tab) {
    int idx = blockIdx.x * blockDim.x + threadIdx.x;   // h*N2 + n
    if (idx >= H_ * N2_) return;
    int h = idx >> 5, n = idx & 31;
    float dt = expf(log_dt[h]);
    float e  = expf(-0.5f * dt);
    float th = PI_ * (float)n * dt;
    float lr = e * cosf(th), li = e * sinf(th);
    float ar = -0.5f, ai = PI_ * (float)n;
    float den = ar * ar + ai * ai;
    float x = lr - 1.0f, y = li;
    float nr = (x * ar + y * ai) / den;
    float ni = (y * ar - x * ai) / den;
    float cr = C_re[idx], ci = C_im[idx];
    tab[idx] = make_float4(lr, li, cr * nr - ci * ni, cr * ni + ci * nr);
}

// ---------------------------------------------------------------------------
// K1 v2: chunk-local recurrence, 4 lanes per (b,h,c), 8 modes per lane.
// Per timestep: 8 independent mode updates, then 4-lane butterfly reduce.
// Lane q stores output element l+q (coalesced 16B per group).
// ---------------------------------------------------------------------------
__global__ void __launch_bounds__(256)
k1_chunk(const float* __restrict__ u, const float4* __restrict__ tab,
         float* __restrict__ g, float2* __restrict__ ES) {
    int t  = blockIdx.x * 256 + threadIdx.x;  // 4 threads per (b,h,c)
    int q  = t & 3;                           // mode sub-block 0..3
    int gi = t >> 2;                          // b*(H*NC) + h*NC + c
    int c  = gi & (NC_ - 1);
    int h  = (gi >> 4) & (H_ - 1);
    int b  = gi >> 13;

    float lr[8], li[8], Cr[8], Ci[8], sr[8], si[8];
#pragma unroll
    for (int j = 0; j < 8; ++j) {
        float4 v = tab[h * N2_ + q * 8 + j];
        lr[j] = v.x; li[j] = v.y; Cr[j] = v.z; Ci[j] = v.w;
        sr[j] = 0.0f; si[j] = 0.0f;
    }
    size_t base = ((size_t)(b * H_ + h)) * L_ + (size_t)c * LC_;
    const float* up = u + base;
    float* gp = g + base;

    for (int l = 0; l < LC_; l += 4) {
        float4 u4 = *(const float4*)(up + l);
        float uv[4] = {u4.x, u4.y, u4.z, u4.w};
        float keep = 0.0f;
#pragma unroll
        for (int jj = 0; jj < 4; ++jj) {
            float uj = uv[jj];
            float p0 = 0.f, p1 = 0.f;
#pragma unroll
            for (int n = 0; n < 8; ++n) {
                float nsr = fmaf(lr[n], sr[n], fmaf(-li[n], si[n], uj));
                float nsi = fmaf(lr[n], si[n], li[n] * sr[n]);
                sr[n] = nsr; si[n] = nsi;
                float term = fmaf(Cr[n], nsr, -Ci[n] * nsi);
                if (n & 1) p1 += term; else p0 += term;
            }
            float partial = p0 + p1;
            partial += __shfl_xor(partial, 1, 64);
            partial += __shfl_xor(partial, 2, 64);
            if (jj == q) keep = 2.0f * partial;
        }
        gp[l + q] = keep;
    }
    float2* es = ES + (size_t)gi * N2_ + q * 8;
#pragma unroll
    for (int n = 0; n < 8; ++n) es[n] = make_float2(sr[n], si[n]);
}

// ---------------------------------------------------------------------------
// K2: per-(b,h,n) serial scan over chunks: S(c) = lam^Lc * S(c-1) + E(c-1).
// In-place: ES slot c is read (=E(c)) then overwritten with S(c).
// ---------------------------------------------------------------------------
__global__ void k2_scan(const float* __restrict__ log_dt, float2* __restrict__ ES) {
    int t = blockIdx.x * 256 + threadIdx.x;   // bh*N2 + n
    if (t >= B_ * H_ * N2_) return;
    int n  = t & 31;
    int h  = (t >> 5) & (H_ - 1);
    int bh = t >> 5;
    float dt = expf(log_dt[h]);
    float e  = expf(-0.5f * dt * (float)LC_);
    float th = PI_ * (float)n * dt * (float)LC_;
    float Lr = e * cosf(th), Li = e * sinf(th);
    float cr = 0.0f, ci = 0.0f;
    float2* base = ES + (size_t)bh * NC_ * N2_ + n;
#pragma unroll
    for (int c = 0; c < NC_; ++c) {
        float2 Ev = base[(size_t)c * N2_];
        base[(size_t)c * N2_] = make_float2(cr, ci);
        float ncr = fmaf(Lr, cr, fmaf(-Li, ci, Ev.x));
        float nci = fmaf(Lr, ci, fmaf(Li, cr, Ev.y));
        cr = ncr; ci = nci;
    }
}

// ---------------------------------------------------------------------------
// K3 v2: carry correction + u*D + exact GELU, same 4-lane/8-mode split.
// ---------------------------------------------------------------------------
__global__ void __launch_bounds__(256)
k3_fix(const float* __restrict__ u, const float* __restrict__ D,
       const float4* __restrict__ tab, const float2* __restrict__ ES,
       float* __restrict__ g) {
    int t  = blockIdx.x * 256 + threadIdx.x;
    int q  = t & 3;
    int gi = t >> 2;
    int c  = gi & (NC_ - 1);
    int h  = (gi >> 4) & (H_ - 1);
    int b  = gi >> 13;

    float lr[8], li[8], Cr[8], Ci[8], pr[8], pi[8];
    const float2* es = ES + (size_t)gi * N2_ + q * 8;
#pragma unroll
    for (int j = 0; j < 8; ++j) {
        float4 v = tab[h * N2_ + q * 8 + j];
        lr[j] = v.x; li[j] = v.y; Cr[j] = v.z; Ci[j] = v.w;
        float2 S = es[j];
        pr[j] = fmaf(lr[j], S.x, -li[j] * S.y);   // lam^(l+1) S at l=0
        pi[j] = fmaf(lr[j], S.y,  li[j] * S.x);
    }
    float d = D[h];
    size_t base = ((size_t)(b * H_ + h)) * L_ + (size_t)c * LC_;
    const float* up = u + base;
    float* gp = g + base;

    for (int l = 0; l < LC_; l += 4) {
        float4 u4 = *(const float4*)(up + l);
        float4 g4 = *(const float4*)(gp + l);
        float uv[4] = {u4.x, u4.y, u4.z, u4.w};
        float gv[4] = {g4.x, g4.y, g4.z, g4.w};
        float corr = 0.0f;
#pragma unroll
        for (int jj = 0; jj < 4; ++jj) {
            float p0 = 0.f, p1 = 0.f;
#pragma unroll
            for (int n = 0; n < 8; ++n) {
                float term = fmaf(Cr[n], pr[n], -Ci[n] * pi[n]);
                if (n & 1) p1 += term; else p0 += term;
                float npr = fmaf(lr[n], pr[n], -li[n] * pi[n]);
                float npi = fmaf(lr[n], pi[n],  li[n] * pr[n]);
                pr[n] = npr; pi[n] = npi;
            }
            float partial = p0 + p1;
            partial += __shfl_xor(partial, 1, 64);
            partial += __shfl_xor(partial, 2, 64);
            if (jj == q) corr = 2.0f * partial;
        }
        float yv = gv[q] + corr + d * uv[q];
        gp[l + q] = 0.5f * yv * (1.0f + erff(yv * 0.70710678118654752f));
    }
}

// ---------------------------------------------------------------------------
// Simple f32 tiled GEMM: C[M,N] = act(A[M,K] @ B[K,N] + bias)
// 64x64 tile, BK=16, 256 threads, 4x4 per thread.
// ---------------------------------------------------------------------------
template<bool TANH>
__global__ void __launch_bounds__(256)
gemm_bias_act(const float* __restrict__ A, const float* __restrict__ Bm,
              const float* __restrict__ bias, float* __restrict__ C,
              int M, int N, int K) {
    const int BM = 64, BN = 64, BK = 16;
    __shared__ float As[BK][BM];
    __shared__ float Bs[BK][BN];
    int tid = threadIdx.x;
    int tx = tid & 15, ty = tid >> 4;
    int row0 = blockIdx.y * BM, col0 = blockIdx.x * BN;

    int arow = tid >> 2;          // 0..63
    int acol = (tid & 3) * 4;     // 0,4,8,12
    int brow = tid >> 4;          // 0..15
    int bcol = (tid & 15) * 4;    // 0..60

    float acc[4][4] = {};
    for (int k0 = 0; k0 < K; k0 += BK) {
        float4 av = *(const float4*)&A[(size_t)(row0 + arow) * K + k0 + acol];
        float4 bv = *(const float4*)&Bm[(size_t)(k0 + brow) * N + col0 + bcol];
        As[acol + 0][arow] = av.x;
        As[acol + 1][arow] = av.y;
        As[acol + 2][arow] = av.z;
        As[acol + 3][arow] = av.w;
        *(float4*)&Bs[brow][bcol] = bv;
        __syncthreads();
#pragma unroll
        for (int kk = 0; kk < BK; ++kk) {
            float4 a = *(const float4*)&As[kk][ty * 4];
            float4 b = *(const float4*)&Bs[kk][tx * 4];
            float avv[4] = {a.x, a.y, a.z, a.w};
            float bvv[4] = {b.x, b.y, b.z, b.w};
#pragma unroll
            for (int i = 0; i < 4; ++i)
#pragma unroll
                for (int j = 0; j < 4; ++j)
                    acc[i][j] = fmaf(avv[i], bvv[j], acc[i][j]);
        }
        __syncthreads();
    }
#pragma unroll
    for (int i = 0; i < 4; ++i) {
        int r = row0 + ty * 4 + i;
        float* op = &C[(size_t)r * N + col0 + tx * 4];
        float4 bb = *(const float4*)&bias[col0 + tx * 4];
        float bv[4] = {bb.x, bb.y, bb.z, bb.w};
        float vals[4];
#pragma unroll
        for (int j = 0; j < 4; ++j) {
            float v = acc[i][j] + bv[j];
            vals[j] = TANH ? tanhf(v) : v;
        }
        *(float4*)op = make_float4(vals[0], vals[1], vals[2], vals[3]);
    }
}

// ---------------------------------------------------------------------------
extern "C" void kernel_launch(void* const* d_in, const int* in_sizes, int n_in,
                              void* d_out, int out_size, void* d_ws, size_t ws_size,
                              hipStream_t stream) {
    const float* u     = (const float*)d_in[0];
    const float* D     = (const float*)d_in[1];
    const float* logdt = (const float*)d_in[2];
    const float* C_re  = (const float*)d_in[3];
    const float* C_im  = (const float*)d_in[4];
    const float* W1    = (const float*)d_in[5];
    const float* b1    = (const float*)d_in[6];
    const float* W2    = (const float*)d_in[7];
    const float* b2    = (const float*)d_in[8];
    float* out = (float*)d_out;

    float*  ws  = (float*)d_ws;
    float4* tab = (float4*)ws;                                  // H*N2 float4
    float*  g   = ws + (size_t)H_ * N2_ * 4;                    // B*H*L
    float*  tbuf= g  + (size_t)B_ * H_ * L_;                    // B*H*2H
    float2* ES  = (float2*)(tbuf + (size_t)B_ * H_ * 2 * H_);   // B*H*NC*N2 cplx

    k0_table<<<(H_ * N2_ + 255) / 256, 256, 0, stream>>>(logdt, C_re, C_im, tab);
    k1_chunk<<<B_ * H_ * NC_ * 4 / 256, 256, 0, stream>>>(u, tab, g, ES);
    k2_scan<<<B_ * H_ * N2_ / 256, 256, 0, stream>>>(logdt, ES);
    k3_fix<<<B_ * H_ * NC_ * 4 / 256, 256, 0, stream>>>(u, D, tab, ES, g);

    gemm_bias_act<true ><<<dim3(2 * H_ / 64, B_ * H_ / 64), 256, 0, stream>>>(
        g, W1, b1, tbuf, B_ * H_, 2 * H_, L_);
    gemm_bias_act<false><<<dim3(H_ / 64, B_ * H_ / 64), 256, 0, stream>>>(
        tbuf, W2, b2, out, B_ * H_, H_, 2 * H_);
}

// Round 3
// 318.769 us; speedup vs baseline: 6.1867x; 2.5945x over previous
//
#include <hip/hip_runtime.h>
#include <math.h>

#define B_  16
#define H_  512
#define L_  2048
#define N2_ 32
#define NC_ 16
#define LC_ 128   // L_/NC_
#define PI_ 3.14159265358979323846f

typedef __attribute__((ext_vector_type(8))) short short8;
typedef __attribute__((ext_vector_type(4))) float f32x4;

__device__ __forceinline__ short f2bf(float x) {
    unsigned u = __builtin_bit_cast(unsigned, x);
    u += 0x7fffu + ((u >> 16) & 1u);           // round-to-nearest-even
    return (short)(u >> 16);
}

// ---------------------------------------------------------------------------
// K0: per-(h,n) table: lambda = exp(dt*A), C' = (C_re+iC_im)*(lambda-1)/A
// ---------------------------------------------------------------------------
__global__ void k0_table(const float* __restrict__ log_dt,
                         const float* __restrict__ C_re,
                         const float* __restrict__ C_im,
                         float4* __restrict__ tab) {
    int idx = blockIdx.x * blockDim.x + threadIdx.x;   // h*N2 + n
    if (idx >= H_ * N2_) return;
    int h = idx >> 5, n = idx & 31;
    float dt = expf(log_dt[h]);
    float e  = expf(-0.5f * dt);
    float th = PI_ * (float)n * dt;
    float lr = e * cosf(th), li = e * sinf(th);
    float ar = -0.5f, ai = PI_ * (float)n;
    float den = ar * ar + ai * ai;
    float x = lr - 1.0f, y = li;
    float nr = (x * ar + y * ai) / den;
    float ni = (y * ar - x * ai) / den;
    float cr = C_re[idx], ci = C_im[idx];
    tab[idx] = make_float4(lr, li, cr * nr - ci * ni, cr * ni + ci * nr);
}

// ---------------------------------------------------------------------------
// W transpose + f32->bf16: Wt[n][k] = bf16(W[k][n])
// ---------------------------------------------------------------------------
__global__ void __launch_bounds__(256)
wtrans(const float* __restrict__ W, short* __restrict__ Wt, int K, int N) {
    __shared__ short tile[32][33];
    int bk = blockIdx.x * 32, bn = blockIdx.y * 32;
    int tx = threadIdx.x & 31, ty = threadIdx.x >> 5;   // ty 0..7
#pragma unroll
    for (int i = 0; i < 4; ++i)
        tile[ty + i * 8][tx] = f2bf(W[(size_t)(bk + ty + i * 8) * N + bn + tx]);
    __syncthreads();
#pragma unroll
    for (int i = 0; i < 4; ++i)
        Wt[(size_t)(bn + ty + i * 8) * K + bk + tx] = tile[tx][ty + i * 8];
}

// ---------------------------------------------------------------------------
// K1: chunk-local recurrence, 4 lanes per (b,h,c), 8 modes per lane.
// ---------------------------------------------------------------------------
__global__ void __launch_bounds__(256)
k1_chunk(const float* __restrict__ u, const float4* __restrict__ tab,
         float* __restrict__ g, float2* __restrict__ ES) {
    int t  = blockIdx.x * 256 + threadIdx.x;
    int q  = t & 3;
    int gi = t >> 2;
    int c  = gi & (NC_ - 1);
    int h  = (gi >> 4) & (H_ - 1);
    int b  = gi >> 13;

    float lr[8], li[8], Cr[8], Ci[8], sr[8], si[8];
#pragma unroll
    for (int j = 0; j < 8; ++j) {
        float4 v = tab[h * N2_ + q * 8 + j];
        lr[j] = v.x; li[j] = v.y; Cr[j] = v.z; Ci[j] = v.w;
        sr[j] = 0.0f; si[j] = 0.0f;
    }
    size_t base = ((size_t)(b * H_ + h)) * L_ + (size_t)c * LC_;
    const float* up = u + base;
    float* gp = g + base;

    for (int l = 0; l < LC_; l += 4) {
        float4 u4 = *(const float4*)(up + l);
        float uv[4] = {u4.x, u4.y, u4.z, u4.w};
        float keep = 0.0f;
#pragma unroll
        for (int jj = 0; jj < 4; ++jj) {
            float uj = uv[jj];
            float p0 = 0.f, p1 = 0.f;
#pragma unroll
            for (int n = 0; n < 8; ++n) {
                float nsr = fmaf(lr[n], sr[n], fmaf(-li[n], si[n], uj));
                float nsi = fmaf(lr[n], si[n], li[n] * sr[n]);
                sr[n] = nsr; si[n] = nsi;
                float term = fmaf(Cr[n], nsr, -Ci[n] * nsi);
                if (n & 1) p1 += term; else p0 += term;
            }
            float partial = p0 + p1;
            partial += __shfl_xor(partial, 1, 64);
            partial += __shfl_xor(partial, 2, 64);
            if (jj == q) keep = 2.0f * partial;
        }
        gp[l + q] = keep;
    }
    float2* es = ES + (size_t)gi * N2_ + q * 8;
#pragma unroll
    for (int n = 0; n < 8; ++n) es[n] = make_float2(sr[n], si[n]);
}

// ---------------------------------------------------------------------------
// K2: per-(b,h,n) serial scan over chunks (exclusive -> S at chunk start).
// ---------------------------------------------------------------------------
__global__ void k2_scan(const float* __restrict__ log_dt, float2* __restrict__ ES) {
    int t = blockIdx.x * 256 + threadIdx.x;
    if (t >= B_ * H_ * N2_) return;
    int n  = t & 31;
    int h  = (t >> 5) & (H_ - 1);
    int bh = t >> 5;
    float dt = expf(log_dt[h]);
    float e  = expf(-0.5f * dt * (float)LC_);
    float th = PI_ * (float)n * dt * (float)LC_;
    float Lr = e * cosf(th), Li = e * sinf(th);
    float cr = 0.0f, ci = 0.0f;
    float2* base = ES + (size_t)bh * NC_ * N2_ + n;
#pragma unroll
    for (int c = 0; c < NC_; ++c) {
        float2 Ev = base[(size_t)c * N2_];
        base[(size_t)c * N2_] = make_float2(cr, ci);
        float ncr = fmaf(Lr, cr, fmaf(-Li, ci, Ev.x));
        float nci = fmaf(Lr, ci, fmaf(Li, cr, Ev.y));
        cr = ncr; ci = nci;
    }
}

// ---------------------------------------------------------------------------
// K3: carry correction + u*D + exact GELU; writes bf16 for the MFMA GEMM.
// ---------------------------------------------------------------------------
__global__ void __launch_bounds__(256)
k3_fix(const float* __restrict__ u, const float* __restrict__ D,
       const float4* __restrict__ tab, const float2* __restrict__ ES,
       const float* __restrict__ g, short* __restrict__ gbf) {
    int t  = blockIdx.x * 256 + threadIdx.x;
    int q  = t & 3;
    int gi = t >> 2;
    int c  = gi & (NC_ - 1);
    int h  = (gi >> 4) & (H_ - 1);
    int b  = gi >> 13;

    float lr[8], li[8], Cr[8], Ci[8], pr[8], pi[8];
    const float2* es = ES + (size_t)gi * N2_ + q * 8;
#pragma unroll
    for (int j = 0; j < 8; ++j) {
        float4 v = tab[h * N2_ + q * 8 + j];
        lr[j] = v.x; li[j] = v.y; Cr[j] = v.z; Ci[j] = v.w;
        float2 S = es[j];
        pr[j] = fmaf(lr[j], S.x, -li[j] * S.y);
        pi[j] = fmaf(lr[j], S.y,  li[j] * S.x);
    }
    float d = D[h];
    size_t base = ((size_t)(b * H_ + h)) * L_ + (size_t)c * LC_;
    const float* up = u + base;
    const float* gp = g + base;
    short* op = gbf + base;

    for (int l = 0; l < LC_; l += 4) {
        float4 u4 = *(const float4*)(up + l);
        float4 g4 = *(const float4*)(gp + l);
        float uv[4] = {u4.x, u4.y, u4.z, u4.w};
        float gv[4] = {g4.x, g4.y, g4.z, g4.w};
        float corr = 0.0f;
#pragma unroll
        for (int jj = 0; jj < 4; ++jj) {
            float p0 = 0.f, p1 = 0.f;
#pragma unroll
            for (int n = 0; n < 8; ++n) {
                float term = fmaf(Cr[n], pr[n], -Ci[n] * pi[n]);
                if (n & 1) p1 += term; else p0 += term;
                float npr = fmaf(lr[n], pr[n], -li[n] * pi[n]);
                float npi = fmaf(lr[n], pi[n],  li[n] * pr[n]);
                pr[n] = npr; pi[n] = npi;
            }
            float partial = p0 + p1;
            partial += __shfl_xor(partial, 1, 64);
            partial += __shfl_xor(partial, 2, 64);
            if (jj == q) corr = 2.0f * partial;
        }
        float yv = gv[q] + corr + d * uv[q];
        float o = 0.5f * yv * (1.0f + erff(yv * 0.70710678118654752f));
        op[l + q] = f2bf(o);
    }
}

// ---------------------------------------------------------------------------
// bf16 MFMA GEMM: C = act(A @ Bt^T + bias). A: MxK bf16 row-major,
// Bt: NxK bf16 row-major (pre-transposed weights). 128x128 tile, BK=32,
// 4 waves (2x2), 64x64 per wave, 16x16x32 MFMA, frag-contiguous LDS.
// ---------------------------------------------------------------------------
template<bool TANH, bool OUTBF>
__global__ void __launch_bounds__(256)
gemm_mfma(const short* __restrict__ A, const short* __restrict__ Bt,
          const float* __restrict__ bias, void* __restrict__ Cout,
          int M, int N, int K) {
    __shared__ short As[4 * 128 * 8];   // [kblk][row][8]
    __shared__ short Bs[4 * 128 * 8];   // [kblk][col][8]
    int tid  = threadIdx.x;
    int lane = tid & 63;
    int wave = tid >> 6;
    int wm = wave >> 1, wn = wave & 1;
    int lrow = lane & 15, kblk = lane >> 4;
    int row0 = blockIdx.y * 128, col0 = blockIdx.x * 128;

    // staging: 2 threads per row, 16 k each (one kblk pair)
    int srow = tid >> 1;
    int skh  = (tid & 1) * 16;
    const short* Ag = A  + (size_t)(row0 + srow) * K + skh;
    const short* Bg = Bt + (size_t)(col0 + srow) * K + skh;
    int sidx0 = ((skh >> 3) + 0) * 1024 + srow * 8;
    int sidx1 = ((skh >> 3) + 1) * 1024 + srow * 8;

    f32x4 acc[4][4] = {};
    short8 av[2], bv[2];
    av[0] = *(const short8*)(Ag);
    av[1] = *(const short8*)(Ag + 8);
    bv[0] = *(const short8*)(Bg);
    bv[1] = *(const short8*)(Bg + 8);

    for (int k0 = 0; k0 < K; k0 += 32) {
        __syncthreads();
        *(short8*)&As[sidx0] = av[0];
        *(short8*)&As[sidx1] = av[1];
        *(short8*)&Bs[sidx0] = bv[0];
        *(short8*)&Bs[sidx1] = bv[1];
        __syncthreads();
        if (k0 + 32 < K) {
            const short* Ag2 = Ag + k0 + 32;
            const short* Bg2 = Bg + k0 + 32;
            av[0] = *(const short8*)(Ag2);
            av[1] = *(const short8*)(Ag2 + 8);
            bv[0] = *(const short8*)(Bg2);
            bv[1] = *(const short8*)(Bg2 + 8);
        }
        short8 af[4], bf[4];
#pragma unroll
        for (int m = 0; m < 4; ++m)
            af[m] = *(const short8*)&As[kblk * 1024 + (wm * 64 + m * 16 + lrow) * 8];
#pragma unroll
        for (int n = 0; n < 4; ++n)
            bf[n] = *(const short8*)&Bs[kblk * 1024 + (wn * 64 + n * 16 + lrow) * 8];
#pragma unroll
        for (int m = 0; m < 4; ++m)
#pragma unroll
            for (int n = 0; n < 4; ++n)
                acc[m][n] = __builtin_amdgcn_mfma_f32_16x16x32_bf16(
                    af[m], bf[n], acc[m][n], 0, 0, 0);
    }

    // epilogue: C/D layout col=lane&15, row=(lane>>4)*4+reg
#pragma unroll
    for (int n = 0; n < 4; ++n) {
        int col = col0 + wn * 64 + n * 16 + lrow;
        float bb = bias[col];
#pragma unroll
        for (int m = 0; m < 4; ++m) {
            int rowb = row0 + wm * 64 + m * 16 + kblk * 4;
#pragma unroll
            for (int r = 0; r < 4; ++r) {
                float v = acc[m][n][r] + bb;
                if (TANH) v = tanhf(v);
                if (OUTBF) ((short*)Cout)[(size_t)(rowb + r) * N + col] = f2bf(v);
                else       ((float*)Cout)[(size_t)(rowb + r) * N + col] = v;
            }
        }
    }
}

// ---------------------------------------------------------------------------
extern "C" void kernel_launch(void* const* d_in, const int* in_sizes, int n_in,
                              void* d_out, int out_size, void* d_ws, size_t ws_size,
                              hipStream_t stream) {
    const float* u     = (const float*)d_in[0];
    const float* D     = (const float*)d_in[1];
    const float* logdt = (const float*)d_in[2];
    const float* C_re  = (const float*)d_in[3];
    const float* C_im  = (const float*)d_in[4];
    const float* W1    = (const float*)d_in[5];
    const float* b1    = (const float*)d_in[6];
    const float* W2    = (const float*)d_in[7];
    const float* b2    = (const float*)d_in[8];
    float* out = (float*)d_out;

    char* p = (char*)d_ws;
    float4* tab = (float4*)p;            p += (size_t)H_ * N2_ * 16;          // 256 KB
    float*  g   = (float*)p;             p += (size_t)B_ * H_ * L_ * 4;       // 64 MB
    float2* ES  = (float2*)p;            p += (size_t)B_ * H_ * NC_ * N2_ * 8;// 32 MB
    short*  gbf = (short*)p;             p += (size_t)B_ * H_ * L_ * 2;       // 32 MB
    short*  tb  = (short*)p;             p += (size_t)B_ * H_ * 2 * H_ * 2;   // 16 MB
    short*  w1t = (short*)p;             p += (size_t)2 * H_ * L_ * 2;        // 4 MB
    short*  w2t = (short*)p;             /* 1 MB */

    k0_table<<<(H_ * N2_ + 255) / 256, 256, 0, stream>>>(logdt, C_re, C_im, tab);
    wtrans<<<dim3(L_ / 32, 2 * H_ / 32), 256, 0, stream>>>(W1, w1t, L_, 2 * H_);
    wtrans<<<dim3(2 * H_ / 32, H_ / 32), 256, 0, stream>>>(W2, w2t, 2 * H_, H_);

    k1_chunk<<<B_ * H_ * NC_ * 4 / 256, 256, 0, stream>>>(u, tab, g, ES);
    k2_scan<<<B_ * H_ * N2_ / 256, 256, 0, stream>>>(logdt, ES);
    k3_fix<<<B_ * H_ * NC_ * 4 / 256, 256, 0, stream>>>(u, D, tab, ES, g, gbf);

    gemm_mfma<true, true ><<<dim3(2 * H_ / 128, B_ * H_ / 128), 256, 0, stream>>>(
        gbf, w1t, b1, tb, B_ * H_, 2 * H_, L_);
    gemm_mfma<false, false><<<dim3(H_ / 128, B_ * H_ / 128), 256, 0, stream>>>(
        tb, w2t, b2, out, B_ * H_, H_, 2 * H_);
}

// Round 4
// 295.679 us; speedup vs baseline: 6.6699x; 1.0781x over previous
//
#include <hip/hip_runtime.h>
#include <math.h>

#define B_  16
#define H_  512
#define L_  2048
#define N2_ 32
#define NC_ 16
#define LC_ 128   // L_/NC_
#define PI_ 3.14159265358979323846f

typedef __attribute__((ext_vector_type(8))) short short8;
typedef __attribute__((ext_vector_type(4))) float f32x4;

__device__ __forceinline__ short f2bf(float x) {
    unsigned u = __builtin_bit_cast(unsigned, x);
    u += 0x7fffu + ((u >> 16) & 1u);           // round-to-nearest-even
    return (short)(u >> 16);
}
__device__ __forceinline__ float bf2f(unsigned short s) {
    unsigned u = ((unsigned)s) << 16;
    return __builtin_bit_cast(float, u);
}

// ---------------------------------------------------------------------------
// K0: per-(h,n) table: lambda = exp(dt*A), C' = (C_re+iC_im)*(lambda-1)/A
// ---------------------------------------------------------------------------
__global__ void k0_table(const float* __restrict__ log_dt,
                         const float* __restrict__ C_re,
                         const float* __restrict__ C_im,
                         float4* __restrict__ tab) {
    int idx = blockIdx.x * blockDim.x + threadIdx.x;   // h*N2 + n
    if (idx >= H_ * N2_) return;
    int h = idx >> 5, n = idx & 31;
    float dt = expf(log_dt[h]);
    float e  = expf(-0.5f * dt);
    float th = PI_ * (float)n * dt;
    float lr = e * cosf(th), li = e * sinf(th);
    float ar = -0.5f, ai = PI_ * (float)n;
    float den = ar * ar + ai * ai;
    float x = lr - 1.0f, y = li;
    float nr = (x * ar + y * ai) / den;
    float ni = (y * ar - x * ai) / den;
    float cr = C_re[idx], ci = C_im[idx];
    tab[idx] = make_float4(lr, li, cr * nr - ci * ni, cr * ni + ci * nr);
}

// ---------------------------------------------------------------------------
// T0: POW[h][m][n] = lambda_n^m, m = 0..128 (complex f32)
// ---------------------------------------------------------------------------
__global__ void t0_pow(const float4* __restrict__ tab, float2* __restrict__ POW) {
    int t = blockIdx.x * 256 + threadIdx.x;   // h*N2 + n
    if (t >= H_ * N2_) return;
    int h = t >> 5, n = t & 31;
    float4 v = tab[t];
    float lr = v.x, li = v.y;
    float pr = 1.0f, pi = 0.0f;
    float2* base = POW + (size_t)h * 129 * N2_ + n;
    for (int m = 0; m <= 128; ++m) {
        base[(size_t)m * N2_] = make_float2(pr, pi);
        float npr = pr * lr - pi * li;
        float npi = pr * li + pi * lr;
        pr = npr; pi = npi;
    }
}

// ---------------------------------------------------------------------------
// ktab[h][m] = 2 * Re sum_n C'_n * lambda_n^m
// ---------------------------------------------------------------------------
__global__ void t_ktab(const float4* __restrict__ tab, const float2* __restrict__ POW,
                       float* __restrict__ ktab) {
    int t = blockIdx.x * 256 + threadIdx.x;   // h*128 + m
    if (t >= H_ * 128) return;
    int h = t >> 7, m = t & 127;
    const float2* P = POW + (size_t)h * 129 * N2_ + (size_t)m * N2_;
    const float4* tb = tab + h * N2_;
    float s = 0.0f;
    for (int n = 0; n < N2_; ++n) {
        float2 p = P[n];
        float4 v = tb[n];
        s += v.z * p.x - v.w * p.y;
    }
    ktab[t] = 2.0f * s;
}

// ---------------------------------------------------------------------------
// T1: fill Psw (pre-swizzled [h][g16][n192][8] bf16) and Vsw ([h][g8][l128][8]).
//  P rows n<128:  Toeplitz  P[n=l][m] = k[l-m] (m<=l else 0)
//  P rows 128+j:  state     P[128+j][m] = Re/Im(lambda^{127-m})  (j=2n / 2n+1)
//  V rows l:      carry     V[l][j] = 2Re(C' lam^{l+1}) / -2Im(...)
// thread = (h*320 + row)*8 + sub
// ---------------------------------------------------------------------------
__global__ void __launch_bounds__(256)
t1_fill(const float4* __restrict__ tab, const float2* __restrict__ POW,
        const float* __restrict__ ktab, short* __restrict__ Psw,
        short* __restrict__ Vsw) {
    int t = blockIdx.x * 256 + threadIdx.x;
    int sub = t & 7;
    int rowg = t >> 3;
    int h = rowg / 320, row = rowg % 320;
    if (row < 192) {
        short8 s0, s1;
        if (row < 128) {
            int l = row;
#pragma unroll
            for (int mm = 0; mm < 8; ++mm) {
                int m0 = sub * 16 + mm, m1 = m0 + 8;
                s0[mm] = (m0 <= l) ? f2bf(ktab[h * 128 + (l - m0)]) : (short)0;
                s1[mm] = (m1 <= l) ? f2bf(ktab[h * 128 + (l - m1)]) : (short)0;
            }
        } else {
            int j = row - 128, nn = j >> 1, part = j & 1;
            const float2* P = POW + (size_t)h * 129 * N2_ + nn;
#pragma unroll
            for (int mm = 0; mm < 8; ++mm) {
                int m0 = sub * 16 + mm, m1 = m0 + 8;
                float2 p0 = P[(size_t)(127 - m0) * N2_];
                float2 p1 = P[(size_t)(127 - m1) * N2_];
                s0[mm] = f2bf(part ? p0.y : p0.x);
                s1[mm] = f2bf(part ? p1.y : p1.x);
            }
        }
        *(short8*)(Psw + ((size_t)(h * 16 + sub * 2 + 0) * 192 + row) * 8) = s0;
        *(short8*)(Psw + ((size_t)(h * 16 + sub * 2 + 1) * 192 + row) * 8) = s1;
    } else {
        int l = row - 192;
        const float2* P = POW + (size_t)h * 129 * N2_ + (size_t)(l + 1) * N2_;
        const float4* tb = tab + h * N2_;
        short8 s;
#pragma unroll
        for (int jj = 0; jj < 8; ++jj) {
            int j = sub * 8 + jj, nn = j >> 1;
            float2 p = P[nn];
            float4 cv = tb[nn];
            float re = cv.z * p.x - cv.w * p.y;
            float im = cv.z * p.y + cv.w * p.x;
            s[jj] = f2bf((j & 1) ? -2.0f * im : 2.0f * re);
        }
        *(short8*)(Vsw + ((size_t)(h * 8 + sub) * 128 + l) * 8) = s;
    }
}

// ---------------------------------------------------------------------------
// conv_mfma: per (h, mh): Out(128x192) = U(128x128) @ P_h^T via MFMA.
// cols 0..127 -> Ybuf (bf16 local conv), cols 128..191 -> E (f32 end-states).
// ---------------------------------------------------------------------------
__global__ void __launch_bounds__(256)
conv_mfma(const float* __restrict__ u, const short* __restrict__ Psw,
          float* __restrict__ E, short* __restrict__ Ybuf) {
    __shared__ short Ps[16 * 192 * 8];   // 48 KB [g][n][8]
    __shared__ short As[4 * 128 * 8];    //  8 KB [g][row][8], one K-step
    int h = blockIdx.x, mh = blockIdx.y;
    int tid = threadIdx.x;
    {
        const short8* Pg = (const short8*)(Psw + (size_t)h * 24576);
        short8* PsV = (short8*)Ps;
#pragma unroll
        for (int j = 0; j < 12; ++j) PsV[tid + j * 256] = Pg[tid + j * 256];
    }
    int row = tid >> 1, half = tid & 1;
    int R = mh * 128 + row, b = R >> 4, c = R & 15;
    const float* up = u + ((size_t)(b * H_ + h)) * L_ + (size_t)c * LC_ + half * 16;
    short8* AsV = (short8*)As;

    int lane = tid & 63, wave = tid >> 6;
    int wm = wave >> 1, wn = wave & 1;
    int lrow = lane & 15, lk = lane >> 4;
    const short8* AsF = (const short8*)As;
    const short8* PsF = (const short8*)Ps;

    f32x4 acc[4][6] = {};
    float4 fv0 = *(const float4*)(up + 0);
    float4 fv1 = *(const float4*)(up + 4);
    float4 fv2 = *(const float4*)(up + 8);
    float4 fv3 = *(const float4*)(up + 12);
    for (int ks = 0; ks < 4; ++ks) {
        __syncthreads();
        short8 s0, s1;
        s0[0] = f2bf(fv0.x); s0[1] = f2bf(fv0.y); s0[2] = f2bf(fv0.z); s0[3] = f2bf(fv0.w);
        s0[4] = f2bf(fv1.x); s0[5] = f2bf(fv1.y); s0[6] = f2bf(fv1.z); s0[7] = f2bf(fv1.w);
        s1[0] = f2bf(fv2.x); s1[1] = f2bf(fv2.y); s1[2] = f2bf(fv2.z); s1[3] = f2bf(fv2.w);
        s1[4] = f2bf(fv3.x); s1[5] = f2bf(fv3.y); s1[6] = f2bf(fv3.z); s1[7] = f2bf(fv3.w);
        AsV[(half * 2 + 0) * 128 + row] = s0;
        AsV[(half * 2 + 1) * 128 + row] = s1;
        __syncthreads();
        if (ks < 3) {
            const float* nx = up + (ks + 1) * 32;
            fv0 = *(const float4*)(nx + 0);
            fv1 = *(const float4*)(nx + 4);
            fv2 = *(const float4*)(nx + 8);
            fv3 = *(const float4*)(nx + 12);
        }
        short8 af[4], bf[6];
#pragma unroll
        for (int m = 0; m < 4; ++m)
            af[m] = AsF[lk * 128 + wm * 64 + m * 16 + lrow];
#pragma unroll
        for (int n = 0; n < 6; ++n)
            bf[n] = PsF[(ks * 4 + lk) * 192 + wn * 96 + n * 16 + lrow];
#pragma unroll
        for (int m = 0; m < 4; ++m)
#pragma unroll
            for (int n = 0; n < 6; ++n)
                acc[m][n] = __builtin_amdgcn_mfma_f32_16x16x32_bf16(
                    af[m], bf[n], acc[m][n], 0, 0, 0);
    }
    // epilogue: C/D layout col=lane&15, row=(lane>>4)*4+reg
#pragma unroll
    for (int nf = 0; nf < 6; ++nf) {
        int col = wn * 96 + nf * 16 + lrow;
#pragma unroll
        for (int mf = 0; mf < 4; ++mf) {
            int rb = wm * 64 + mf * 16 + lk * 4;
#pragma unroll
            for (int r = 0; r < 4; ++r) {
                int rr = rb + r;
                float vv = acc[mf][nf][r];
                if (col < 128) {
                    Ybuf[(size_t)h * 32768 + (size_t)(mh * 128 + rr) * 128 + col] = f2bf(vv);
                } else {
                    int Rr = mh * 128 + rr, bb = Rr >> 4, cc = Rr & 15;
                    E[((size_t)(bb * H_ + h) * NC_ + cc) * 64 + (col - 128)] = vv;
                }
            }
        }
    }
}

// ---------------------------------------------------------------------------
// K2: per-(b,h,n) serial scan over chunks (exclusive -> S at chunk start).
// ---------------------------------------------------------------------------
__global__ void k2_scan(const float* __restrict__ log_dt, float2* __restrict__ ES) {
    int t = blockIdx.x * 256 + threadIdx.x;
    if (t >= B_ * H_ * N2_) return;
    int n  = t & 31;
    int h  = (t >> 5) & (H_ - 1);
    int bh = t >> 5;
    float dt = expf(log_dt[h]);
    float e  = expf(-0.5f * dt * (float)LC_);
    float th = PI_ * (float)n * dt * (float)LC_;
    float Lr = e * cosf(th), Li = e * sinf(th);
    float cr = 0.0f, ci = 0.0f;
    float2* base = ES + (size_t)bh * NC_ * N2_ + n;
#pragma unroll
    for (int c = 0; c < NC_; ++c) {
        float2 Ev = base[(size_t)c * N2_];
        base[(size_t)c * N2_] = make_float2(cr, ci);
        float ncr = fmaf(Lr, cr, fmaf(-Li, ci, Ev.x));
        float nci = fmaf(Lr, ci, fmaf(Li, cr, Ev.y));
        cr = ncr; ci = nci;
    }
}

// ---------------------------------------------------------------------------
// dfix_mfma: per (h, mh): Carry(128x128) = S(128x64) @ V_h^T via MFMA;
// epilogue: yv = Ylocal + Carry + D*u; exact GELU; write gbf (bf16).
// ---------------------------------------------------------------------------
__global__ void __launch_bounds__(256)
dfix_mfma(const float* __restrict__ u, const float* __restrict__ Dv,
          const float* __restrict__ ES, const short* __restrict__ Vsw,
          const short* __restrict__ Ybuf, short* __restrict__ gbf) {
    __shared__ short Sa[8 * 128 * 8];   // 16 KB [g][row][8]
    __shared__ short Vb[8 * 128 * 8];   // 16 KB [g][l][8]
    int h = blockIdx.x, mh = blockIdx.y;
    int tid = threadIdx.x;
    {
        const short8* Vg = (const short8*)(Vsw + (size_t)h * 8192);
        short8* VbV = (short8*)Vb;
#pragma unroll
        for (int j = 0; j < 4; ++j) VbV[tid + j * 256] = Vg[tid + j * 256];
    }
    int row = tid >> 1, half = tid & 1;
    int R = mh * 128 + row, b = R >> 4, c = R & 15;
    {
        const float* sp = ES + ((size_t)(b * H_ + h) * NC_ + c) * 64 + half * 32;
        short8* SaV = (short8*)Sa;
#pragma unroll
        for (int gg = 0; gg < 4; ++gg) {
            float4 f0 = *(const float4*)(sp + gg * 8);
            float4 f1 = *(const float4*)(sp + gg * 8 + 4);
            short8 s;
            s[0] = f2bf(f0.x); s[1] = f2bf(f0.y); s[2] = f2bf(f0.z); s[3] = f2bf(f0.w);
            s[4] = f2bf(f1.x); s[5] = f2bf(f1.y); s[6] = f2bf(f1.z); s[7] = f2bf(f1.w);
            SaV[(half * 4 + gg) * 128 + row] = s;
        }
    }
    __syncthreads();
    int lane = tid & 63, wave = tid >> 6;
    int wm = wave >> 1, wn = wave & 1;
    int lrow = lane & 15, lk = lane >> 4;
    const short8* SaF = (const short8*)Sa;
    const short8* VbF = (const short8*)Vb;
    f32x4 acc[4][4] = {};
#pragma unroll
    for (int ks = 0; ks < 2; ++ks) {
        int g = ks * 4 + lk;
        short8 af[4], bf[4];
#pragma unroll
        for (int m = 0; m < 4; ++m)
            af[m] = SaF[g * 128 + wm * 64 + m * 16 + lrow];
#pragma unroll
        for (int n = 0; n < 4; ++n)
            bf[n] = VbF[g * 128 + wn * 64 + n * 16 + lrow];
#pragma unroll
        for (int m = 0; m < 4; ++m)
#pragma unroll
            for (int n = 0; n < 4; ++n)
                acc[m][n] = __builtin_amdgcn_mfma_f32_16x16x32_bf16(
                    af[m], bf[n], acc[m][n], 0, 0, 0);
    }
    float dv = Dv[h];
#pragma unroll
    for (int nf = 0; nf < 4; ++nf) {
        int l = wn * 64 + nf * 16 + lrow;
#pragma unroll
        for (int mf = 0; mf < 4; ++mf) {
            int rb = wm * 64 + mf * 16 + lk * 4;
#pragma unroll
            for (int r = 0; r < 4; ++r) {
                int rr = rb + r;
                int Rr = mh * 128 + rr, bb = Rr >> 4, cc = Rr & 15;
                size_t gaddr = ((size_t)(bb * H_ + h)) * L_ + (size_t)cc * LC_ + l;
                float yloc = bf2f(((const unsigned short*)Ybuf)[(size_t)h * 32768 + (size_t)Rr * 128 + l]);
                float uv = u[gaddr];
                float yv = yloc + acc[mf][nf][r] + dv * uv;
                float o = 0.5f * yv * (1.0f + erff(yv * 0.70710678118654752f));
                gbf[gaddr] = f2bf(o);
            }
        }
    }
}

// ---------------------------------------------------------------------------
// W transpose + f32->bf16: Wt[n][k] = bf16(W[k][n])
// ---------------------------------------------------------------------------
__global__ void __launch_bounds__(256)
wtrans(const float* __restrict__ W, short* __restrict__ Wt, int K, int N) {
    __shared__ short tile[32][33];
    int bk = blockIdx.x * 32, bn = blockIdx.y * 32;
    int tx = threadIdx.x & 31, ty = threadIdx.x >> 5;   // ty 0..7
#pragma unroll
    for (int i = 0; i < 4; ++i)
        tile[ty + i * 8][tx] = f2bf(W[(size_t)(bk + ty + i * 8) * N + bn + tx]);
    __syncthreads();
#pragma unroll
    for (int i = 0; i < 4; ++i)
        Wt[(size_t)(bn + ty + i * 8) * K + bk + tx] = tile[tx][ty + i * 8];
}

// ---------------------------------------------------------------------------
// bf16 MFMA GEMM: C = act(A @ Bt^T + bias). 128x128 tile, BK=32, 4 waves.
// ---------------------------------------------------------------------------
template<bool TANH, bool OUTBF>
__global__ void __launch_bounds__(256)
gemm_mfma(const short* __restrict__ A, const short* __restrict__ Bt,
          const float* __restrict__ bias, void* __restrict__ Cout,
          int M, int N, int K) {
    __shared__ short As[4 * 128 * 8];   // [kblk][row][8]
    __shared__ short Bs[4 * 128 * 8];   // [kblk][col][8]
    int tid  = threadIdx.x;
    int lane = tid & 63;
    int wave = tid >> 6;
    int wm = wave >> 1, wn = wave & 1;
    int lrow = lane & 15, kblk = lane >> 4;
    int row0 = blockIdx.y * 128, col0 = blockIdx.x * 128;

    int srow = tid >> 1;
    int skh  = (tid & 1) * 16;
    const short* Ag = A  + (size_t)(row0 + srow) * K + skh;
    const short* Bg = Bt + (size_t)(col0 + srow) * K + skh;
    int sidx0 = ((skh >> 3) + 0) * 1024 + srow * 8;
    int sidx1 = ((skh >> 3) + 1) * 1024 + srow * 8;

    f32x4 acc[4][4] = {};
    short8 av[2], bv[2];
    av[0] = *(const short8*)(Ag);
    av[1] = *(const short8*)(Ag + 8);
    bv[0] = *(const short8*)(Bg);
    bv[1] = *(const short8*)(Bg + 8);

    for (int k0 = 0; k0 < K; k0 += 32) {
        __syncthreads();
        *(short8*)&As[sidx0] = av[0];
        *(short8*)&As[sidx1] = av[1];
        *(short8*)&Bs[sidx0] = bv[0];
        *(short8*)&Bs[sidx1] = bv[1];
        __syncthreads();
        if (k0 + 32 < K) {
            const short* Ag2 = Ag + k0 + 32;
            const short* Bg2 = Bg + k0 + 32;
            av[0] = *(const short8*)(Ag2);
            av[1] = *(const short8*)(Ag2 + 8);
            bv[0] = *(const short8*)(Bg2);
            bv[1] = *(const short8*)(Bg2 + 8);
        }
        short8 af[4], bf[4];
#pragma unroll
        for (int m = 0; m < 4; ++m)
            af[m] = *(const short8*)&As[kblk * 1024 + (wm * 64 + m * 16 + lrow) * 8];
#pragma unroll
        for (int n = 0; n < 4; ++n)
            bf[n] = *(const short8*)&Bs[kblk * 1024 + (wn * 64 + n * 16 + lrow) * 8];
#pragma unroll
        for (int m = 0; m < 4; ++m)
#pragma unroll
            for (int n = 0; n < 4; ++n)
                acc[m][n] = __builtin_amdgcn_mfma_f32_16x16x32_bf16(
                    af[m], bf[n], acc[m][n], 0, 0, 0);
    }
#pragma unroll
    for (int n = 0; n < 4; ++n) {
        int col = col0 + wn * 64 + n * 16 + lrow;
        float bb = bias[col];
#pragma unroll
        for (int m = 0; m < 4; ++m) {
            int rowb = row0 + wm * 64 + m * 16 + kblk * 4;
#pragma unroll
            for (int r = 0; r < 4; ++r) {
                float v = acc[m][n][r] + bb;
                if (TANH) v = tanhf(v);
                if (OUTBF) ((short*)Cout)[(size_t)(rowb + r) * N + col] = f2bf(v);
                else       ((float*)Cout)[(size_t)(rowb + r) * N + col] = v;
            }
        }
    }
}

// ---------------------------------------------------------------------------
extern "C" void kernel_launch(void* const* d_in, const int* in_sizes, int n_in,
                              void* d_out, int out_size, void* d_ws, size_t ws_size,
                              hipStream_t stream) {
    const float* u     = (const float*)d_in[0];
    const float* D     = (const float*)d_in[1];
    const float* logdt = (const float*)d_in[2];
    const float* C_re  = (const float*)d_in[3];
    const float* C_im  = (const float*)d_in[4];
    const float* W1    = (const float*)d_in[5];
    const float* b1    = (const float*)d_in[6];
    const float* W2    = (const float*)d_in[7];
    const float* b2    = (const float*)d_in[8];
    float* out = (float*)d_out;

    char* p = (char*)d_ws;
    float4* tab = (float4*)p;            p += 262144;      // H*N2*16
    char* regionA = p;                   p += 33554432;    // POW+ktab, later Ybuf
    float2* POW  = (float2*)regionA;                       // 512*129*32*8 = 16.9 MB
    float*  ktab = (float*)(regionA + 16908288);           // 512*128*4
    short*  Ybuf = (short*)regionA;                        // 512*256*128*2 = 32 MB
    short* Psw = (short*)p;              p += 25165824;    // 512*192*128*2
    short* Vsw = (short*)p;              p += 8388608;     // 512*128*64*2
    float* E   = (float*)p;              p += 33554432;    // 8192*16*64*4
    short* gbf = (short*)p;              p += 33554432;    // B*H*L*2
    short* tb  = (short*)p;              p += 16777216;    // 8192*1024*2
    short* w1t = (short*)p;              p += 4194304;
    short* w2t = (short*)p;

    k0_table<<<H_ * N2_ / 256, 256, 0, stream>>>(logdt, C_re, C_im, tab);
    t0_pow  <<<H_ * N2_ / 256, 256, 0, stream>>>(tab, POW);
    t_ktab  <<<H_ * 128 / 256, 256, 0, stream>>>(tab, POW, ktab);
    t1_fill <<<H_ * 320 * 8 / 256, 256, 0, stream>>>(tab, POW, ktab, Psw, Vsw);
    wtrans  <<<dim3(L_ / 32, 2 * H_ / 32), 256, 0, stream>>>(W1, w1t, L_, 2 * H_);
    wtrans  <<<dim3(2 * H_ / 32, H_ / 32), 256, 0, stream>>>(W2, w2t, 2 * H_, H_);

    conv_mfma<<<dim3(H_, 2), 256, 0, stream>>>(u, Psw, E, Ybuf);
    k2_scan  <<<B_ * H_ * N2_ / 256, 256, 0, stream>>>(logdt, (float2*)E);
    dfix_mfma<<<dim3(H_, 2), 256, 0, stream>>>(u, D, E, Vsw, Ybuf, gbf);

    gemm_mfma<true, true ><<<dim3(2 * H_ / 128, B_ * H_ / 128), 256, 0, stream>>>(
        gbf, w1t, b1, tb, B_ * H_, 2 * H_, L_);
    gemm_mfma<false, false><<<dim3(H_ / 128, B_ * H_ / 128), 256, 0, stream>>>(
        tb, w2t, b2, out, B_ * H_, H_, 2 * H_);
}

// Round 5
// 214.781 us; speedup vs baseline: 9.1821x; 1.3767x over previous
//
#include <hip/hip_runtime.h>
#include <math.h>

#define B_  16
#define H_  512
#define L_  2048
#define N2_ 32
#define NC_ 16
#define LC_ 128   // L_/NC_
#define PI_ 3.14159265358979323846f

typedef __attribute__((ext_vector_type(8))) short short8;
typedef __attribute__((ext_vector_type(4))) float f32x4;

__device__ __forceinline__ short f2bf(float x) {
    unsigned u = __builtin_bit_cast(unsigned, x);
    u += 0x7fffu + ((u >> 16) & 1u);           // round-to-nearest-even
    return (short)(u >> 16);
}
__device__ __forceinline__ float bf2f(unsigned short s) {
    unsigned u = ((unsigned)s) << 16;
    return __builtin_bit_cast(float, u);
}

// ---------------------------------------------------------------------------
// K0: per-(h,n) table: lambda = exp(dt*A), C' = (C_re+iC_im)*(lambda-1)/A
// ---------------------------------------------------------------------------
__global__ void k0_table(const float* __restrict__ log_dt,
                         const float* __restrict__ C_re,
                         const float* __restrict__ C_im,
                         float4* __restrict__ tab) {
    int idx = blockIdx.x * blockDim.x + threadIdx.x;   // h*N2 + n
    if (idx >= H_ * N2_) return;
    int h = idx >> 5, n = idx & 31;
    float dt = expf(log_dt[h]);
    float e  = expf(-0.5f * dt);
    float th = PI_ * (float)n * dt;
    float lr = e * cosf(th), li = e * sinf(th);
    float ar = -0.5f, ai = PI_ * (float)n;
    float den = ar * ar + ai * ai;
    float x = lr - 1.0f, y = li;
    float nr = (x * ar + y * ai) / den;
    float ni = (y * ar - x * ai) / den;
    float cr = C_re[idx], ci = C_im[idx];
    tab[idx] = make_float4(lr, li, cr * nr - ci * ni, cr * ni + ci * nr);
}

// ---------------------------------------------------------------------------
// T0: POW[h][m][n] = lambda_n^m, m = 0..128 (complex f32)
// ---------------------------------------------------------------------------
__global__ void t0_pow(const float4* __restrict__ tab, float2* __restrict__ POW) {
    int t = blockIdx.x * 256 + threadIdx.x;   // h*N2 + n
    if (t >= H_ * N2_) return;
    int h = t >> 5, n = t & 31;
    float4 v = tab[t];
    float lr = v.x, li = v.y;
    float pr = 1.0f, pi = 0.0f;
    float2* base = POW + (size_t)h * 129 * N2_ + n;
    for (int m = 0; m <= 128; ++m) {
        base[(size_t)m * N2_] = make_float2(pr, pi);
        float npr = pr * lr - pi * li;
        float npi = pr * li + pi * lr;
        pr = npr; pi = npi;
    }
}

// ---------------------------------------------------------------------------
// ktab[h][m] = 2 * Re sum_n C'_n * lambda_n^m
// ---------------------------------------------------------------------------
__global__ void t_ktab(const float4* __restrict__ tab, const float2* __restrict__ POW,
                       float* __restrict__ ktab) {
    int t = blockIdx.x * 256 + threadIdx.x;   // h*128 + m
    if (t >= H_ * 128) return;
    int h = t >> 7, m = t & 127;
    const float2* P = POW + (size_t)h * 129 * N2_ + (size_t)m * N2_;
    const float4* tb = tab + h * N2_;
    float s = 0.0f;
    for (int n = 0; n < N2_; ++n) {
        float2 p = P[n];
        float4 v = tb[n];
        s += v.z * p.x - v.w * p.y;
    }
    ktab[t] = 2.0f * s;
}

// ---------------------------------------------------------------------------
// T1: fill Psw (pre-swizzled [h][g16][n192][8] bf16) and Vsw ([h][g8][l128][8]).
// ---------------------------------------------------------------------------
__global__ void __launch_bounds__(256)
t1_fill(const float4* __restrict__ tab, const float2* __restrict__ POW,
        const float* __restrict__ ktab, short* __restrict__ Psw,
        short* __restrict__ Vsw) {
    int t = blockIdx.x * 256 + threadIdx.x;
    int sub = t & 7;
    int rowg = t >> 3;
    int h = rowg / 320, row = rowg % 320;
    if (row < 192) {
        short8 s0, s1;
        if (row < 128) {
            int l = row;
#pragma unroll
            for (int mm = 0; mm < 8; ++mm) {
                int m0 = sub * 16 + mm, m1 = m0 + 8;
                s0[mm] = (m0 <= l) ? f2bf(ktab[h * 128 + (l - m0)]) : (short)0;
                s1[mm] = (m1 <= l) ? f2bf(ktab[h * 128 + (l - m1)]) : (short)0;
            }
        } else {
            int j = row - 128, nn = j >> 1, part = j & 1;
            const float2* P = POW + (size_t)h * 129 * N2_ + nn;
#pragma unroll
            for (int mm = 0; mm < 8; ++mm) {
                int m0 = sub * 16 + mm, m1 = m0 + 8;
                float2 p0 = P[(size_t)(127 - m0) * N2_];
                float2 p1 = P[(size_t)(127 - m1) * N2_];
                s0[mm] = f2bf(part ? p0.y : p0.x);
                s1[mm] = f2bf(part ? p1.y : p1.x);
            }
        }
        *(short8*)(Psw + ((size_t)(h * 16 + sub * 2 + 0) * 192 + row) * 8) = s0;
        *(short8*)(Psw + ((size_t)(h * 16 + sub * 2 + 1) * 192 + row) * 8) = s1;
    } else {
        int l = row - 192;
        const float2* P = POW + (size_t)h * 129 * N2_ + (size_t)(l + 1) * N2_;
        const float4* tb = tab + h * N2_;
        short8 s;
#pragma unroll
        for (int jj = 0; jj < 8; ++jj) {
            int j = sub * 8 + jj, nn = j >> 1;
            float2 p = P[nn];
            float4 cv = tb[nn];
            float re = cv.z * p.x - cv.w * p.y;
            float im = cv.z * p.y + cv.w * p.x;
            s[jj] = f2bf((j & 1) ? -2.0f * im : 2.0f * re);
        }
        *(short8*)(Vsw + ((size_t)(h * 8 + sub) * 128 + l) * 8) = s;
    }
}

// ---------------------------------------------------------------------------
// conv_mfma: per (h, mh): Out(128x192) = U(128x128) @ P_h^T via MFMA.
// cols 0..127 -> Ybuf (bf16 local conv, (b,h,l) layout), cols 128..191 -> E.
// ---------------------------------------------------------------------------
__global__ void __launch_bounds__(256)
conv_mfma(const float* __restrict__ u, const short* __restrict__ Psw,
          float* __restrict__ E, short* __restrict__ Ybuf) {
    __shared__ short Ps[16 * 192 * 8];   // 48 KB [g][n][8]
    __shared__ short As[4 * 128 * 8];    //  8 KB [g][row][8], one K-step
    int h = blockIdx.x, mh = blockIdx.y;
    int tid = threadIdx.x;
    {
        const short8* Pg = (const short8*)(Psw + (size_t)h * 24576);
        short8* PsV = (short8*)Ps;
#pragma unroll
        for (int j = 0; j < 12; ++j) PsV[tid + j * 256] = Pg[tid + j * 256];
    }
    int row = tid >> 1, half = tid & 1;
    int R = mh * 128 + row, b = R >> 4, c = R & 15;
    const float* up = u + ((size_t)(b * H_ + h)) * L_ + (size_t)c * LC_ + half * 16;
    short8* AsV = (short8*)As;

    int lane = tid & 63, wave = tid >> 6;
    int wm = wave >> 1, wn = wave & 1;
    int lrow = lane & 15, lk = lane >> 4;
    const short8* AsF = (const short8*)As;
    const short8* PsF = (const short8*)Ps;

    f32x4 acc[4][6] = {};
    float4 fv0 = *(const float4*)(up + 0);
    float4 fv1 = *(const float4*)(up + 4);
    float4 fv2 = *(const float4*)(up + 8);
    float4 fv3 = *(const float4*)(up + 12);
    for (int ks = 0; ks < 4; ++ks) {
        __syncthreads();
        short8 s0, s1;
        s0[0] = f2bf(fv0.x); s0[1] = f2bf(fv0.y); s0[2] = f2bf(fv0.z); s0[3] = f2bf(fv0.w);
        s0[4] = f2bf(fv1.x); s0[5] = f2bf(fv1.y); s0[6] = f2bf(fv1.z); s0[7] = f2bf(fv1.w);
        s1[0] = f2bf(fv2.x); s1[1] = f2bf(fv2.y); s1[2] = f2bf(fv2.z); s1[3] = f2bf(fv2.w);
        s1[4] = f2bf(fv3.x); s1[5] = f2bf(fv3.y); s1[6] = f2bf(fv3.z); s1[7] = f2bf(fv3.w);
        AsV[(half * 2 + 0) * 128 + row] = s0;
        AsV[(half * 2 + 1) * 128 + row] = s1;
        __syncthreads();
        if (ks < 3) {
            const float* nx = up + (ks + 1) * 32;
            fv0 = *(const float4*)(nx + 0);
            fv1 = *(const float4*)(nx + 4);
            fv2 = *(const float4*)(nx + 8);
            fv3 = *(const float4*)(nx + 12);
        }
        short8 af[4], bf[6];
#pragma unroll
        for (int m = 0; m < 4; ++m)
            af[m] = AsF[lk * 128 + wm * 64 + m * 16 + lrow];
#pragma unroll
        for (int n = 0; n < 6; ++n)
            bf[n] = PsF[(ks * 4 + lk) * 192 + wn * 96 + n * 16 + lrow];
#pragma unroll
        for (int m = 0; m < 4; ++m)
#pragma unroll
            for (int n = 0; n < 6; ++n)
                acc[m][n] = __builtin_amdgcn_mfma_f32_16x16x32_bf16(
                    af[m], bf[n], acc[m][n], 0, 0, 0);
    }
    // epilogue: C/D layout col=lane&15, row=(lane>>4)*4+reg
#pragma unroll
    for (int nf = 0; nf < 6; ++nf) {
        int col = wn * 96 + nf * 16 + lrow;
#pragma unroll
        for (int mf = 0; mf < 4; ++mf) {
            int rb = wm * 64 + mf * 16 + lk * 4;
#pragma unroll
            for (int r = 0; r < 4; ++r) {
                int rr = rb + r;
                int Rr = mh * 128 + rr, bb = Rr >> 4, cc = Rr & 15;
                float vv = acc[mf][nf][r];
                if (col < 128) {
                    Ybuf[((size_t)(bb * H_ + h)) * L_ + (size_t)cc * LC_ + col] = f2bf(vv);
                } else {
                    E[((size_t)(bb * H_ + h) * NC_ + cc) * 64 + (col - 128)] = vv;
                }
            }
        }
    }
}

// ---------------------------------------------------------------------------
// K2: per-(b,h,n) serial scan over chunks (exclusive -> S at chunk start).
// ---------------------------------------------------------------------------
__global__ void k2_scan(const float* __restrict__ log_dt, float2* __restrict__ ES) {
    int t = blockIdx.x * 256 + threadIdx.x;
    if (t >= B_ * H_ * N2_) return;
    int n  = t & 31;
    int h  = (t >> 5) & (H_ - 1);
    int bh = t >> 5;
    float dt = expf(log_dt[h]);
    float e  = expf(-0.5f * dt * (float)LC_);
    float th = PI_ * (float)n * dt * (float)LC_;
    float Lr = e * cosf(th), Li = e * sinf(th);
    float cr = 0.0f, ci = 0.0f;
    float2* base = ES + (size_t)bh * NC_ * N2_ + n;
#pragma unroll
    for (int c = 0; c < NC_; ++c) {
        float2 Ev = base[(size_t)c * N2_];
        base[(size_t)c * N2_] = make_float2(cr, ci);
        float ncr = fmaf(Lr, cr, fmaf(-Li, ci, Ev.x));
        float nci = fmaf(Lr, ci, fmaf(Li, cr, Ev.y));
        cr = ncr; ci = nci;
    }
}

// ---------------------------------------------------------------------------
// dcarry_mfma: per (h, mh): Carry(128x128) = S(128x64) @ V_h^T via MFMA.
// Pure GEMM; writes bf16 carry into gbf ((b,h,l) layout), no loads in epilogue.
// ---------------------------------------------------------------------------
__global__ void __launch_bounds__(256)
dcarry_mfma(const float* __restrict__ ES, const short* __restrict__ Vsw,
            short* __restrict__ gbf) {
    __shared__ short Sa[8 * 128 * 8];   // 16 KB [g][row][8]
    __shared__ short Vb[8 * 128 * 8];   // 16 KB [g][l][8]
    int h = blockIdx.x, mh = blockIdx.y;
    int tid = threadIdx.x;
    {
        const short8* Vg = (const short8*)(Vsw + (size_t)h * 8192);
        short8* VbV = (short8*)Vb;
#pragma unroll
        for (int j = 0; j < 4; ++j) VbV[tid + j * 256] = Vg[tid + j * 256];
    }
    int row = tid >> 1, half = tid & 1;
    int R = mh * 128 + row, b = R >> 4, c = R & 15;
    {
        const float* sp = ES + ((size_t)(b * H_ + h) * NC_ + c) * 64 + half * 32;
        short8* SaV = (short8*)Sa;
#pragma unroll
        for (int gg = 0; gg < 4; ++gg) {
            float4 f0 = *(const float4*)(sp + gg * 8);
            float4 f1 = *(const float4*)(sp + gg * 8 + 4);
            short8 s;
            s[0] = f2bf(f0.x); s[1] = f2bf(f0.y); s[2] = f2bf(f0.z); s[3] = f2bf(f0.w);
            s[4] = f2bf(f1.x); s[5] = f2bf(f1.y); s[6] = f2bf(f1.z); s[7] = f2bf(f1.w);
            SaV[(half * 4 + gg) * 128 + row] = s;
        }
    }
    __syncthreads();
    int lane = tid & 63, wave = tid >> 6;
    int wm = wave >> 1, wn = wave & 1;
    int lrow = lane & 15, lk = lane >> 4;
    const short8* SaF = (const short8*)Sa;
    const short8* VbF = (const short8*)Vb;
    f32x4 acc[4][4] = {};
#pragma unroll
    for (int ks = 0; ks < 2; ++ks) {
        int g = ks * 4 + lk;
        short8 af[4], bf[4];
#pragma unroll
        for (int m = 0; m < 4; ++m)
            af[m] = SaF[g * 128 + wm * 64 + m * 16 + lrow];
#pragma unroll
        for (int n = 0; n < 4; ++n)
            bf[n] = VbF[g * 128 + wn * 64 + n * 16 + lrow];
#pragma unroll
        for (int m = 0; m < 4; ++m)
#pragma unroll
            for (int n = 0; n < 4; ++n)
                acc[m][n] = __builtin_amdgcn_mfma_f32_16x16x32_bf16(
                    af[m], bf[n], acc[m][n], 0, 0, 0);
    }
#pragma unroll
    for (int nf = 0; nf < 4; ++nf) {
        int l = wn * 64 + nf * 16 + lrow;
#pragma unroll
        for (int mf = 0; mf < 4; ++mf) {
            int rb = wm * 64 + mf * 16 + lk * 4;
#pragma unroll
            for (int r = 0; r < 4; ++r) {
                int Rr = mh * 128 + rb + r, bb = Rr >> 4, cc = Rr & 15;
                size_t gaddr = ((size_t)(bb * H_ + h)) * L_ + (size_t)cc * LC_ + l;
                gbf[gaddr] = f2bf(acc[mf][nf][r]);
            }
        }
    }
}

// ---------------------------------------------------------------------------
// egelu: fused elementwise: gbf = bf16(GELU(Ybuf + gbf + D*u)).
// Fully coalesced, grid-stride, 8 elems/thread/iter.
// ---------------------------------------------------------------------------
__global__ void __launch_bounds__(256)
egelu(const float* __restrict__ u, const float* __restrict__ Dv,
      const short* __restrict__ Ybuf, short* __restrict__ gbf) {
    size_t total = (size_t)B_ * H_ * L_ / 8;
    size_t stride = (size_t)gridDim.x * 256;
    for (size_t i = (size_t)blockIdx.x * 256 + threadIdx.x; i < total; i += stride) {
        size_t e = i * 8;
        int h = (int)((e >> 11) & (H_ - 1));
        float dv = Dv[h];
        short8 yv = *(const short8*)(Ybuf + e);
        short8 cv = *(const short8*)(gbf + e);
        float4 u0 = *(const float4*)(u + e);
        float4 u1 = *(const float4*)(u + e + 4);
        float uu[8] = {u0.x, u0.y, u0.z, u0.w, u1.x, u1.y, u1.z, u1.w};
        short8 o;
#pragma unroll
        for (int j = 0; j < 8; ++j) {
            float y = bf2f((unsigned short)yv[j]) + bf2f((unsigned short)cv[j]) + dv * uu[j];
            o[j] = f2bf(0.5f * y * (1.0f + erff(y * 0.70710678118654752f)));
        }
        *(short8*)(gbf + e) = o;
    }
}

// ---------------------------------------------------------------------------
// W transpose + f32->bf16: Wt[n][k] = bf16(W[k][n])
// ---------------------------------------------------------------------------
__global__ void __launch_bounds__(256)
wtrans(const float* __restrict__ W, short* __restrict__ Wt, int K, int N) {
    __shared__ short tile[32][33];
    int bk = blockIdx.x * 32, bn = blockIdx.y * 32;
    int tx = threadIdx.x & 31, ty = threadIdx.x >> 5;   // ty 0..7
#pragma unroll
    for (int i = 0; i < 4; ++i)
        tile[ty + i * 8][tx] = f2bf(W[(size_t)(bk + ty + i * 8) * N + bn + tx]);
    __syncthreads();
#pragma unroll
    for (int i = 0; i < 4; ++i)
        Wt[(size_t)(bn + ty + i * 8) * K + bk + tx] = tile[tx][ty + i * 8];
}

// ---------------------------------------------------------------------------
// bf16 MFMA GEMM: C = act(A @ Bt^T + bias). 128x128 tile, BK=32, 4 waves.
// ---------------------------------------------------------------------------
template<bool TANH, bool OUTBF>
__global__ void __launch_bounds__(256)
gemm_mfma(const short* __restrict__ A, const short* __restrict__ Bt,
          const float* __restrict__ bias, void* __restrict__ Cout,
          int M, int N, int K) {
    __shared__ short As[4 * 128 * 8];   // [kblk][row][8]
    __shared__ short Bs[4 * 128 * 8];   // [kblk][col][8]
    int tid  = threadIdx.x;
    int lane = tid & 63;
    int wave = tid >> 6;
    int wm = wave >> 1, wn = wave & 1;
    int lrow = lane & 15, kblk = lane >> 4;
    int row0 = blockIdx.y * 128, col0 = blockIdx.x * 128;

    int srow = tid >> 1;
    int skh  = (tid & 1) * 16;
    const short* Ag = A  + (size_t)(row0 + srow) * K + skh;
    const short* Bg = Bt + (size_t)(col0 + srow) * K + skh;
    int sidx0 = ((skh >> 3) + 0) * 1024 + srow * 8;
    int sidx1 = ((skh >> 3) + 1) * 1024 + srow * 8;

    f32x4 acc[4][4] = {};
    short8 av[2], bv[2];
    av[0] = *(const short8*)(Ag);
    av[1] = *(const short8*)(Ag + 8);
    bv[0] = *(const short8*)(Bg);
    bv[1] = *(const short8*)(Bg + 8);

    for (int k0 = 0; k0 < K; k0 += 32) {
        __syncthreads();
        *(short8*)&As[sidx0] = av[0];
        *(short8*)&As[sidx1] = av[1];
        *(short8*)&Bs[sidx0] = bv[0];
        *(short8*)&Bs[sidx1] = bv[1];
        __syncthreads();
        if (k0 + 32 < K) {
            const short* Ag2 = Ag + k0 + 32;
            const short* Bg2 = Bg + k0 + 32;
            av[0] = *(const short8*)(Ag2);
            av[1] = *(const short8*)(Ag2 + 8);
            bv[0] = *(const short8*)(Bg2);
            bv[1] = *(const short8*)(Bg2 + 8);
        }
        short8 af[4], bf[4];
#pragma unroll
        for (int m = 0; m < 4; ++m)
            af[m] = *(const short8*)&As[kblk * 1024 + (wm * 64 + m * 16 + lrow) * 8];
#pragma unroll
        for (int n = 0; n < 4; ++n)
            bf[n] = *(const short8*)&Bs[kblk * 1024 + (wn * 64 + n * 16 + lrow) * 8];
#pragma unroll
        for (int m = 0; m < 4; ++m)
#pragma unroll
            for (int n = 0; n < 4; ++n)
                acc[m][n] = __builtin_amdgcn_mfma_f32_16x16x32_bf16(
                    af[m], bf[n], acc[m][n], 0, 0, 0);
    }
#pragma unroll
    for (int n = 0; n < 4; ++n) {
        int col = col0 + wn * 64 + n * 16 + lrow;
        float bb = bias[col];
#pragma unroll
        for (int m = 0; m < 4; ++m) {
            int rowb = row0 + wm * 64 + m * 16 + kblk * 4;
#pragma unroll
            for (int r = 0; r < 4; ++r) {
                float v = acc[m][n][r] + bb;
                if (TANH) v = tanhf(v);
                if (OUTBF) ((short*)Cout)[(size_t)(rowb + r) * N + col] = f2bf(v);
                else       ((float*)Cout)[(size_t)(rowb + r) * N + col] = v;
            }
        }
    }
}

// ---------------------------------------------------------------------------
extern "C" void kernel_launch(void* const* d_in, const int* in_sizes, int n_in,
                              void* d_out, int out_size, void* d_ws, size_t ws_size,
                              hipStream_t stream) {
    const float* u     = (const float*)d_in[0];
    const float* D     = (const float*)d_in[1];
    const float* logdt = (const float*)d_in[2];
    const float* C_re  = (const float*)d_in[3];
    const float* C_im  = (const float*)d_in[4];
    const float* W1    = (const float*)d_in[5];
    const float* b1    = (const float*)d_in[6];
    const float* W2    = (const float*)d_in[7];
    const float* b2    = (const float*)d_in[8];
    float* out = (float*)d_out;

    char* p = (char*)d_ws;
    float4* tab = (float4*)p;            p += 262144;      // H*N2*16
    char* regionA = p;                   p += 33554432;    // POW+ktab, later Ybuf
    float2* POW  = (float2*)regionA;                       // 512*129*32*8 = 16.9 MB
    float*  ktab = (float*)(regionA + 16908288);           // 512*128*4
    short*  Ybuf = (short*)regionA;                        // B*H*L*2 = 32 MB (b,h,l)
    short* Psw = (short*)p;              p += 25165824;    // 512*192*128*2
    short* Vsw = (short*)p;              p += 8388608;     // 512*128*64*2
    float* E   = (float*)p;              p += 33554432;    // 8192*16*64*4
    short* gbf = (short*)p;              p += 33554432;    // B*H*L*2
    short* tb  = (short*)p;              p += 16777216;    // 8192*1024*2
    short* w1t = (short*)p;              p += 4194304;
    short* w2t = (short*)p;

    k0_table<<<H_ * N2_ / 256, 256, 0, stream>>>(logdt, C_re, C_im, tab);
    t0_pow  <<<H_ * N2_ / 256, 256, 0, stream>>>(tab, POW);
    t_ktab  <<<H_ * 128 / 256, 256, 0, stream>>>(tab, POW, ktab);
    t1_fill <<<H_ * 320 * 8 / 256, 256, 0, stream>>>(tab, POW, ktab, Psw, Vsw);
    wtrans  <<<dim3(L_ / 32, 2 * H_ / 32), 256, 0, stream>>>(W1, w1t, L_, 2 * H_);
    wtrans  <<<dim3(2 * H_ / 32, H_ / 32), 256, 0, stream>>>(W2, w2t, 2 * H_, H_);

    conv_mfma  <<<dim3(H_, 2), 256, 0, stream>>>(u, Psw, E, Ybuf);
    k2_scan    <<<B_ * H_ * N2_ / 256, 256, 0, stream>>>(logdt, (float2*)E);
    dcarry_mfma<<<dim3(H_, 2), 256, 0, stream>>>(E, Vsw, gbf);
    egelu      <<<2048, 256, 0, stream>>>(u, D, Ybuf, gbf);

    gemm_mfma<true, true ><<<dim3(2 * H_ / 128, B_ * H_ / 128), 256, 0, stream>>>(
        gbf, w1t, b1, tb, B_ * H_, 2 * H_, L_);
    gemm_mfma<false, false><<<dim3(H_ / 128, B_ * H_ / 128), 256, 0, stream>>>(
        tb, w2t, b2, out, B_ * H_, H_, 2 * H_);
}